// Round 1
// baseline (212.297 us; speedup 1.0000x reference)
//
#include <hip/hip_runtime.h>
#include <hip/hip_bf16.h>
#include <math.h>

// GAT forward, N=4096, F=512, H=8, NH=64. All fp32.
// Sparse-equivalent attention: masked entries contribute exp(-9e15 - m) == 0 in f32.

#define GN 4096
#define GF 512

// ---- pack Ws[H][F][NH] -> Wcat[F][F] with col c = h*64+k ----
__global__ void pack_ws(const float* __restrict__ Ws, float* __restrict__ Wcat) {
    int idx = blockIdx.x * 256 + threadIdx.x;   // 0 .. 512*512-1
    int f = idx >> 9;
    int c = idx & 511;
    int h = c >> 6, k = c & 63;
    Wcat[idx] = Ws[h * (512 * 64) + f * 64 + k];
}

// ---- fp32 GEMM: C[M,Nc] = A[M,K] @ B[K,Nc], tiles 64x64, BK=16 ----
__global__ __launch_bounds__(256) void gemm_f32(const float* __restrict__ A,
                                                const float* __restrict__ B,
                                                float* __restrict__ C,
                                                int M, int K, int Nc) {
    __shared__ float As[16][68];   // As[k][m], padded
    __shared__ float Bs[16][68];   // Bs[k][n], padded
    const int tx = threadIdx.x & 15, ty = threadIdx.x >> 4;
    const int bm = blockIdx.y * 64, bn = blockIdx.x * 64;
    float acc[4][4] = {};
    for (int k0 = 0; k0 < K; k0 += 16) {
        {
            int r = threadIdx.x >> 2, kq = (threadIdx.x & 3) * 4;
            float4 av = *(const float4*)(A + (size_t)(bm + r) * K + k0 + kq);
            As[kq + 0][r] = av.x; As[kq + 1][r] = av.y;
            As[kq + 2][r] = av.z; As[kq + 3][r] = av.w;
            int kr = threadIdx.x >> 4;
            int nq = (threadIdx.x & 15) * 4;
            *(float4*)(&Bs[kr][nq]) = *(const float4*)(B + (size_t)(k0 + kr) * Nc + bn + nq);
        }
        __syncthreads();
        #pragma unroll
        for (int kk = 0; kk < 16; ++kk) {
            float a[4], b[4];
            #pragma unroll
            for (int i = 0; i < 4; ++i) a[i] = As[kk][ty * 4 + i];
            #pragma unroll
            for (int j = 0; j < 4; ++j) b[j] = Bs[kk][tx * 4 + j];
            #pragma unroll
            for (int i = 0; i < 4; ++i)
                #pragma unroll
                for (int j = 0; j < 4; ++j) acc[i][j] += a[i] * b[j];
        }
        __syncthreads();
    }
    #pragma unroll
    for (int i = 0; i < 4; ++i) {
        float4 v = make_float4(acc[i][0], acc[i][1], acc[i][2], acc[i][3]);
        *(float4*)(C + (size_t)(bm + ty * 4 + i) * Nc + bn + tx * 4) = v;
    }
}

// ---- s[h][i] = Wh[i, h*NH .. ] . a1[h], d likewise. One wave per row. ----
template<int H>
__global__ void sd_kernel(const float* __restrict__ Wh, const float* __restrict__ a1,
                          const float* __restrict__ a2, float* __restrict__ s,
                          float* __restrict__ d, int N) {
    constexpr int NH = 512 / H;
    constexpr int G = NH / 8;           // lanes per head group (8 or 64)
    const int wid = threadIdx.x >> 6, lane = threadIdx.x & 63;
    const int row = blockIdx.x * 4 + wid;
    const float4* wr = (const float4*)(Wh + (size_t)row * 512);
    float4 wa = wr[lane * 2], wb = wr[lane * 2 + 1];
    const int h = lane / G;
    const int kb = (lane % G) * 8;
    const float* A1 = a1 + h * NH;
    const float* A2 = a2 + h * NH;
    float w0[8] = {wa.x, wa.y, wa.z, wa.w, wb.x, wb.y, wb.z, wb.w};
    float ps = 0.f, pd = 0.f;
    #pragma unroll
    for (int i = 0; i < 8; ++i) { ps += w0[i] * A1[kb + i]; pd += w0[i] * A2[kb + i]; }
    #pragma unroll
    for (int off = 1; off < G; off <<= 1) {
        ps += __shfl_xor(ps, off);
        pd += __shfl_xor(pd, off);
    }
    if ((lane % G) == 0) { s[h * N + row] = ps; d[h * N + row] = pd; }
}

// ---- attention + aggregate + ELU. One block (256 thr) per row. ----
template<int H>
__global__ __launch_bounds__(256) void attn_kernel(
        const float* __restrict__ Wh, const float* __restrict__ s,
        const float* __restrict__ d, const float* __restrict__ adj,
        float* __restrict__ out, int N) {
    constexpr int F = 512;
    constexpr int NH = F / H;
    constexpr int CAP = 512;
    __shared__ int nbr[CAP];
    __shared__ float p[H][CAP];
    __shared__ float redbuf[4];
    __shared__ int wcnt[4];
    __shared__ float mh[H], lh[H], fh[H];
    const int t = threadIdx.x, lane = t & 63, wid = t >> 6;
    const int row = blockIdx.x;
    const int c0 = t, c1 = t + 256;
    const int h0 = c0 / NH, h1 = c1 / NH;
    if (t < H) { mh[t] = -INFINITY; lh[t] = 0.f; }
    float acc0 = 0.f, acc1 = 0.f;
    __syncthreads();

    auto flush = [&](int M) {
        // M uniform across block; nbr[0..M) valid (synced by caller)
        for (int h = 0; h < H; ++h) {
            const float sh = s[h * N + row];
            float lm = -INFINITY;
            for (int j = t; j < M; j += 256) {
                float e = sh + d[h * N + nbr[j]];
                e = e > 0.f ? e : 0.2f * e;        // leaky relu, slope 0.2
                p[h][j] = e;
                lm = fmaxf(lm, e);
            }
            #pragma unroll
            for (int off = 32; off; off >>= 1) lm = fmaxf(lm, __shfl_xor(lm, off));
            if (lane == 0) redbuf[wid] = lm;
            __syncthreads();
            lm = fmaxf(fmaxf(redbuf[0], redbuf[1]), fmaxf(redbuf[2], redbuf[3]));
            const float mold = mh[h];
            const float mnew = fmaxf(mold, lm);
            __syncthreads();                       // redbuf reuse
            float lsum = 0.f;
            for (int j = t; j < M; j += 256) {
                float pe = expf(p[h][j] - mnew);
                p[h][j] = pe;
                lsum += pe;
            }
            #pragma unroll
            for (int off = 32; off; off >>= 1) lsum += __shfl_xor(lsum, off);
            if (lane == 0) redbuf[wid] = lsum;
            __syncthreads();
            lsum = redbuf[0] + redbuf[1] + redbuf[2] + redbuf[3];
            if (t == 0) {
                float f = expf(mold - mnew);       // 0 on first chunk (mold=-inf)
                fh[h] = f;
                lh[h] = lh[h] * f + lsum;
                mh[h] = mnew;
            }
            __syncthreads();                       // fh visible; redbuf reusable
        }
        // rescale + accumulate: thread owns output cols c0, c1
        acc0 *= fh[h0];
        acc1 *= fh[h1];
        for (int j = 0; j < M; ++j) {
            const float* whr = Wh + (size_t)nbr[j] * F;
            acc0 += p[h0][j] * whr[c0];
            acc1 += p[h1][j] * whr[c1];
        }
        __syncthreads();                           // nbr/p reusable
    };

    int M = 0;
    for (int base = 0; base < N; base += 256) {
        float v = adj[(size_t)row * N + base + t];
        bool pred = v > 0.f;
        unsigned long long mask = __ballot(pred);
        int my = __popcll(mask & ((1ull << lane) - 1ull));
        if (lane == 0) wcnt[wid] = __popcll(mask);
        __syncthreads();
        int wb = M;
        for (int w = 0; w < wid; ++w) wb += wcnt[w];
        if (pred) nbr[wb + my] = base + t;
        M += wcnt[0] + wcnt[1] + wcnt[2] + wcnt[3];
        __syncthreads();
        if (M >= CAP - 256) { flush(M); M = 0; }
    }
    if (M > 0) flush(M);

    const float l0 = lh[h0], l1 = lh[h1];
    float o0 = acc0 / l0, o1 = acc1 / l1;
    o0 = o0 > 0.f ? o0 : expm1f(o0);               // ELU (alpha=1)
    o1 = o1 > 0.f ? o1 : expm1f(o1);
    out[(size_t)row * F + c0] = o0;
    out[(size_t)row * F + c1] = o1;
}

extern "C" void kernel_launch(void* const* d_in, const int* in_sizes, int n_in,
                              void* d_out, int out_size, void* d_ws, size_t ws_size,
                              hipStream_t stream) {
    const float* x   = (const float*)d_in[0];
    // d_in[1] = left (unused by forward)
    const float* adj = (const float*)d_in[2];
    const float* Ws  = (const float*)d_in[3];
    const float* a1  = (const float*)d_in[4];
    const float* a2  = (const float*)d_in[5];
    const float* Wo  = (const float*)d_in[6];
    const float* ao1 = (const float*)d_in[7];
    const float* ao2 = (const float*)d_in[8];
    float* out = (float*)d_out;
    const int N = GN;

    float* ws   = (float*)d_ws;
    float* Wcat = ws;                    // 512*512          = 262144
    float* Wh   = Wcat + 262144;         // 4096*512         = 2097152
    float* sbuf = Wh + 2097152;          // 8*4096           = 32768
    float* dbuf = sbuf + 32768;          // 8*4096           = 32768
    float* hcat = dbuf + 32768;          // 4096*512         = 2097152
    float* Who  = hcat + 2097152;        // 4096*512         = 2097152
    float* sob  = Who + 2097152;         // 4096
    float* dob  = sob + 4096;            // 4096
    // total ~26.5 MB of workspace

    hipLaunchKernelGGL(pack_ws, dim3(1024), dim3(256), 0, stream, Ws, Wcat);
    hipLaunchKernelGGL(gemm_f32, dim3(8, 64), dim3(256), 0, stream, x, Wcat, Wh, 4096, 512, 512);
    hipLaunchKernelGGL(sd_kernel<8>, dim3(1024), dim3(256), 0, stream, Wh, a1, a2, sbuf, dbuf, N);
    hipLaunchKernelGGL(attn_kernel<8>, dim3(4096), dim3(256), 0, stream, Wh, sbuf, dbuf, adj, hcat, N);
    hipLaunchKernelGGL(gemm_f32, dim3(8, 64), dim3(256), 0, stream, hcat, Wo, Who, 4096, 512, 512);
    hipLaunchKernelGGL(sd_kernel<1>, dim3(1024), dim3(256), 0, stream, Who, ao1, ao2, sob, dob, N);
    hipLaunchKernelGGL(attn_kernel<1>, dim3(4096), dim3(256), 0, stream, Who, sob, dob, adj, out, N);
}

// Round 2
// 157.669 us; speedup vs baseline: 1.3465x; 1.3465x over previous
//
#include <hip/hip_runtime.h>
#include <hip/hip_bf16.h>
#include <math.h>

// GAT forward, N=4096, F=512, H=8, NH=64. All fp32.
// Sparse-equivalent attention: masked entries contribute exp(-9e15 - m) == 0 in f32.
// Round 2: one-shot neighbor extraction (CSR u16), head-parallel single-pass softmax.

#define GN 4096
#define GF 512

// ---- pack Ws[H][F][NH] -> Wcat[F][F] with col c = h*64+k ----
__global__ void pack_ws(const float* __restrict__ Ws, float* __restrict__ Wcat) {
    int idx = blockIdx.x * 256 + threadIdx.x;   // 0 .. 512*512-1
    int f = idx >> 9;
    int c = idx & 511;
    int h = c >> 6, k = c & 63;
    Wcat[idx] = Ws[h * (512 * 64) + f * 64 + k];
}

// ---- fp32 GEMM: C[M,Nc] = A[M,K] @ B[K,Nc], tiles 64x64, BK=16 ----
__global__ __launch_bounds__(256) void gemm_f32(const float* __restrict__ A,
                                                const float* __restrict__ B,
                                                float* __restrict__ C,
                                                int M, int K, int Nc) {
    __shared__ float As[16][68];   // As[k][m], padded
    __shared__ float Bs[16][68];   // Bs[k][n], padded
    const int tx = threadIdx.x & 15, ty = threadIdx.x >> 4;
    const int bm = blockIdx.y * 64, bn = blockIdx.x * 64;
    float acc[4][4] = {};
    for (int k0 = 0; k0 < K; k0 += 16) {
        {
            int r = threadIdx.x >> 2, kq = (threadIdx.x & 3) * 4;
            float4 av = *(const float4*)(A + (size_t)(bm + r) * K + k0 + kq);
            As[kq + 0][r] = av.x; As[kq + 1][r] = av.y;
            As[kq + 2][r] = av.z; As[kq + 3][r] = av.w;
            int kr = threadIdx.x >> 4;
            int nq = (threadIdx.x & 15) * 4;
            *(float4*)(&Bs[kr][nq]) = *(const float4*)(B + (size_t)(k0 + kr) * Nc + bn + nq);
        }
        __syncthreads();
        #pragma unroll
        for (int kk = 0; kk < 16; ++kk) {
            float a[4], b[4];
            #pragma unroll
            for (int i = 0; i < 4; ++i) a[i] = As[kk][ty * 4 + i];
            #pragma unroll
            for (int j = 0; j < 4; ++j) b[j] = Bs[kk][tx * 4 + j];
            #pragma unroll
            for (int i = 0; i < 4; ++i)
                #pragma unroll
                for (int j = 0; j < 4; ++j) acc[i][j] += a[i] * b[j];
        }
        __syncthreads();
    }
    #pragma unroll
    for (int i = 0; i < 4; ++i) {
        float4 v = make_float4(acc[i][0], acc[i][1], acc[i][2], acc[i][3]);
        *(float4*)(C + (size_t)(bm + ty * 4 + i) * Nc + bn + tx * 4) = v;
    }
}

// ---- s[h][i] = Wh[i, h*NH ..] . a1[h], d likewise. One wave per row. ----
template<int H>
__global__ void sd_kernel(const float* __restrict__ Wh, const float* __restrict__ a1,
                          const float* __restrict__ a2, float* __restrict__ s,
                          float* __restrict__ d, int N) {
    constexpr int NH = 512 / H;
    constexpr int G = NH / 8;           // lanes per head group (8 or 64)
    const int wid = threadIdx.x >> 6, lane = threadIdx.x & 63;
    const int row = blockIdx.x * 4 + wid;
    const float4* wr = (const float4*)(Wh + (size_t)row * 512);
    float4 wa = wr[lane * 2], wb = wr[lane * 2 + 1];
    const int h = lane / G;
    const int kb = (lane % G) * 8;
    const float* A1 = a1 + h * NH;
    const float* A2 = a2 + h * NH;
    float w0[8] = {wa.x, wa.y, wa.z, wa.w, wb.x, wb.y, wb.z, wb.w};
    float ps = 0.f, pd = 0.f;
    #pragma unroll
    for (int i = 0; i < 8; ++i) { ps += w0[i] * A1[kb + i]; pd += w0[i] * A2[kb + i]; }
    #pragma unroll
    for (int off = 1; off < G; off <<= 1) {
        ps += __shfl_xor(ps, off);
        pd += __shfl_xor(pd, off);
    }
    if ((lane % G) == 0) { s[h * N + row] = ps; d[h * N + row] = pd; }
}

// ---- neighbor extraction: adj row -> compact u16 index list (runs ONCE) ----
__global__ __launch_bounds__(256) void extract_nbrs(const float* __restrict__ adj,
        unsigned short* __restrict__ nbr, int* __restrict__ deg, int N) {
    __shared__ int wtot[4];
    __shared__ int wbase[4];
    const int t = threadIdx.x, lane = t & 63, wid = t >> 6, row = blockIdx.x;
    const float4* arow = (const float4*)(adj + (size_t)row * N);
    unsigned mask16 = 0;
    #pragma unroll
    for (int q = 0; q < 4; ++q) {
        float4 v = arow[t * 4 + q];
        if (v.x > 0.f) mask16 |= 1u << (q * 4 + 0);
        if (v.y > 0.f) mask16 |= 1u << (q * 4 + 1);
        if (v.z > 0.f) mask16 |= 1u << (q * 4 + 2);
        if (v.w > 0.f) mask16 |= 1u << (q * 4 + 3);
    }
    int cnt = __popc(mask16);
    int inc = cnt;
    #pragma unroll
    for (int off = 1; off < 64; off <<= 1) {
        int nv = __shfl_up(inc, off);
        if (lane >= off) inc += nv;
    }
    if (lane == 63) wtot[wid] = inc;
    __syncthreads();
    if (t == 0) {
        int b = 0;
        #pragma unroll
        for (int w = 0; w < 4; ++w) { wbase[w] = b; b += wtot[w]; }
        deg[row] = b;
    }
    __syncthreads();
    int base = wbase[wid] + inc - cnt;   // exclusive prefix
    unsigned short* dst = nbr + (size_t)row * 512 + base;
    int col0 = t * 16;
    int k = 0;
    while (mask16) {
        int b = __ffs(mask16) - 1;
        mask16 &= mask16 - 1;
        dst[k++] = (unsigned short)(col0 + b);
    }
}

// ---- attention + aggregate + ELU. One block (256 thr) per row, single pass. ----
template<int H>
__global__ __launch_bounds__(256) void attn_kernel(
        const float* __restrict__ Wh, const float* __restrict__ s,
        const float* __restrict__ d, const unsigned short* __restrict__ nbr,
        const int* __restrict__ deg, float* __restrict__ out, int N) {
    constexpr int F = 512, NH = F / H, CAP = 512, GS = 256 / H;
    __shared__ int nb[CAP];
    __shared__ float p[H][CAP];
    __shared__ float lred[H];
    __shared__ float red[4];
    const int t = threadIdx.x, lane = t & 63, row = blockIdx.x;
    const int M = deg[row];              // max realistic deg ~80 << CAP
    for (int j = t; j < M; j += 256) nb[j] = nbr[(size_t)row * 512 + j];
    __syncthreads();
    // head-parallel softmax: group of GS threads owns one head
    const int h = t / GS, sub = t % GS;
    const float sh = s[h * N + row];
    const float* dh = d + (size_t)h * N;
    float lm = -INFINITY;
    for (int j = sub; j < M; j += GS) {
        float e = sh + dh[nb[j]];
        e = e > 0.f ? e : 0.2f * e;      // leaky relu, slope 0.2
        p[h][j] = e;
        lm = fmaxf(lm, e);
    }
    if constexpr (GS <= 64) {
        #pragma unroll
        for (int off = GS / 2; off; off >>= 1) lm = fmaxf(lm, __shfl_xor(lm, off));
    } else {
        #pragma unroll
        for (int off = 32; off; off >>= 1) lm = fmaxf(lm, __shfl_xor(lm, off));
        if (lane == 0) red[t >> 6] = lm;
        __syncthreads();
        lm = fmaxf(fmaxf(red[0], red[1]), fmaxf(red[2], red[3]));
    }
    float ls = 0.f;
    for (int j = sub; j < M; j += GS) {
        float pe = expf(p[h][j] - lm);
        p[h][j] = pe;
        ls += pe;
    }
    if constexpr (GS <= 64) {
        #pragma unroll
        for (int off = GS / 2; off; off >>= 1) ls += __shfl_xor(ls, off);
    } else {
        #pragma unroll
        for (int off = 32; off; off >>= 1) ls += __shfl_xor(ls, off);
        __syncthreads();                 // red reuse
        if (lane == 0) red[t >> 6] = ls;
        __syncthreads();
        ls = red[0] + red[1] + red[2] + red[3];
    }
    if (sub == 0) lred[h] = ls;
    __syncthreads();
    // aggregate: thread owns contiguous cols 2t, 2t+1 (same head)
    const int c = 2 * t;
    const int hc = c / NH;
    const float inv = 1.f / lred[hc];
    const float* base = Wh + c;
    float ax = 0.f, ay = 0.f;
    #pragma unroll 4
    for (int j = 0; j < M; ++j) {
        float pw = p[hc][j];             // LDS broadcast within half-wave
        const float2 w = *(const float2*)(base + (size_t)nb[j] * F);
        ax += pw * w.x; ay += pw * w.y;
    }
    ax *= inv; ay *= inv;
    ax = ax > 0.f ? ax : expm1f(ax);     // ELU (alpha=1)
    ay = ay > 0.f ? ay : expm1f(ay);
    out[(size_t)row * F + c] = ax;
    out[(size_t)row * F + c + 1] = ay;
}

extern "C" void kernel_launch(void* const* d_in, const int* in_sizes, int n_in,
                              void* d_out, int out_size, void* d_ws, size_t ws_size,
                              hipStream_t stream) {
    const float* x   = (const float*)d_in[0];
    // d_in[1] = left (unused by forward)
    const float* adj = (const float*)d_in[2];
    const float* Ws  = (const float*)d_in[3];
    const float* a1  = (const float*)d_in[4];
    const float* a2  = (const float*)d_in[5];
    const float* Wo  = (const float*)d_in[6];
    const float* ao1 = (const float*)d_in[7];
    const float* ao2 = (const float*)d_in[8];
    float* out = (float*)d_out;
    const int N = GN;

    float* ws   = (float*)d_ws;
    float* Wcat = ws;                    // 512*512          = 262144
    float* Wh   = Wcat + 262144;         // 4096*512         = 2097152
    float* sbuf = Wh + 2097152;          // 8*4096           = 32768
    float* dbuf = sbuf + 32768;          // 8*4096           = 32768
    float* hcat = dbuf + 32768;          // 4096*512         = 2097152
    float* Who  = hcat + 2097152;        // 4096*512         = 2097152
    float* sob  = Who + 2097152;         // 4096
    float* dob  = sob + 4096;            // 4096
    unsigned short* nbrs = (unsigned short*)(dob + 4096);  // 4096*512 u16 = 4 MB
    int* deg = (int*)(nbrs + 4096 * 512);                  // 4096 ints
    // total ~31 MB of workspace

    hipLaunchKernelGGL(extract_nbrs, dim3(4096), dim3(256), 0, stream, adj, nbrs, deg, N);
    hipLaunchKernelGGL(pack_ws, dim3(1024), dim3(256), 0, stream, Ws, Wcat);
    hipLaunchKernelGGL(gemm_f32, dim3(8, 64), dim3(256), 0, stream, x, Wcat, Wh, 4096, 512, 512);
    hipLaunchKernelGGL(sd_kernel<8>, dim3(1024), dim3(256), 0, stream, Wh, a1, a2, sbuf, dbuf, N);
    hipLaunchKernelGGL(attn_kernel<8>, dim3(4096), dim3(256), 0, stream, Wh, sbuf, dbuf, nbrs, deg, hcat, N);
    hipLaunchKernelGGL(gemm_f32, dim3(8, 64), dim3(256), 0, stream, hcat, Wo, Who, 4096, 512, 512);
    hipLaunchKernelGGL(sd_kernel<1>, dim3(1024), dim3(256), 0, stream, Who, ao1, ao2, sob, dob, N);
    hipLaunchKernelGGL(attn_kernel<1>, dim3(4096), dim3(256), 0, stream, Who, sob, dob, nbrs, deg, out, N);
}

// Round 3
// 157.477 us; speedup vs baseline: 1.3481x; 1.0012x over previous
//
#include <hip/hip_runtime.h>
#include <hip/hip_bf16.h>
#include <math.h>

// GAT forward, N=4096, F=512, H=8, NH=64.
// Round 3: GEMMs on matrix cores via 3-term bf16 split (fp32-accurate),
// B pre-packed transposed hi/lo, LDS-free MFMA GEMM.

#define GN 4096
#define GF 512

typedef __attribute__((ext_vector_type(8))) short bf16x8;
typedef __attribute__((ext_vector_type(4))) float f32x4;

__device__ inline unsigned short f2bf(float f) {
    unsigned u = __float_as_uint(f);
    unsigned r = (u + 0x7fffu + ((u >> 16) & 1u)) >> 16;
    return (unsigned short)r;
}
__device__ inline float bf2f(unsigned short h) {
    return __uint_as_float((unsigned)h << 16);
}
__device__ inline void split2(float v, unsigned short& h, unsigned short& l) {
    h = f2bf(v);
    l = f2bf(v - bf2f(h));
}

// ---- split fp32 array -> hi/lo bf16 arrays (float4 per thread) ----
__global__ __launch_bounds__(256) void split_f32(const float* __restrict__ in,
        unsigned short* __restrict__ hi, unsigned short* __restrict__ lo, int n4) {
    int i = blockIdx.x * 256 + threadIdx.x;
    if (i >= n4) return;
    float4 v = ((const float4*)in)[i];
    ushort4 h, l;
    split2(v.x, h.x, l.x); split2(v.y, h.y, l.y);
    split2(v.z, h.z, l.z); split2(v.w, h.w, l.w);
    ((ushort4*)hi)[i] = h;
    ((ushort4*)lo)[i] = l;
}

// ---- Ws[H][F][NH] -> Bt[c][f] hi/lo, c = h*64+k (transposed, split) ----
__global__ void pack_ws_split(const float* __restrict__ Ws,
        unsigned short* __restrict__ Bthi, unsigned short* __restrict__ Btlo) {
    int idx = blockIdx.x * 256 + threadIdx.x;    // (c,f): f minor
    int c = idx >> 9, f = idx & 511;
    int h = c >> 6, k = c & 63;
    float v = Ws[h * (512 * 64) + f * 64 + k];
    unsigned short hh, ll;
    split2(v, hh, ll);
    Bthi[idx] = hh; Btlo[idx] = ll;
}

// ---- Wo[F][F] -> WoT[c][f] hi/lo ----
__global__ void pack_wo_split(const float* __restrict__ Wo,
        unsigned short* __restrict__ Bthi, unsigned short* __restrict__ Btlo) {
    int idx = blockIdx.x * 256 + threadIdx.x;    // (c,f): f minor
    int c = idx >> 9, f = idx & 511;
    float v = Wo[f * 512 + c];
    unsigned short hh, ll;
    split2(v, hh, ll);
    Bthi[idx] = hh; Btlo[idx] = ll;
}

// ---- MFMA GEMM: C[M,Nc] = A[M,K] @ B[K,Nc]; A as hi/lo [M][K], B as hi/lo [Nc][K] ----
// 64x64 tile per block, 4 waves on 32x32 quadrants, 3-term bf16 split.
__global__ __launch_bounds__(256) void gemm_split(
        const unsigned short* __restrict__ Ahi, const unsigned short* __restrict__ Alo,
        const unsigned short* __restrict__ Bhi, const unsigned short* __restrict__ Blo,
        float* __restrict__ C, int M, int K, int Nc) {
    const int lane = threadIdx.x & 63, wid = threadIdx.x >> 6;
    const int bm = blockIdx.y * 64 + (wid >> 1) * 32;
    const int bn = blockIdx.x * 64 + (wid & 1) * 32;
    const int rl = lane & 15, kb = (lane >> 4) * 8;
    const size_t a0 = (size_t)(bm + rl) * K + kb;
    const size_t a1 = a0 + (size_t)16 * K;
    const size_t b0 = (size_t)(bn + rl) * K + kb;
    const size_t b1 = b0 + (size_t)16 * K;
    f32x4 acc00 = {0,0,0,0}, acc01 = {0,0,0,0}, acc10 = {0,0,0,0}, acc11 = {0,0,0,0};
    #pragma unroll 2
    for (int k = 0; k < K; k += 32) {
        bf16x8 a0h = *(const bf16x8*)(Ahi + a0 + k);
        bf16x8 a0l = *(const bf16x8*)(Alo + a0 + k);
        bf16x8 a1h = *(const bf16x8*)(Ahi + a1 + k);
        bf16x8 a1l = *(const bf16x8*)(Alo + a1 + k);
        bf16x8 b0h = *(const bf16x8*)(Bhi + b0 + k);
        bf16x8 b0l = *(const bf16x8*)(Blo + b0 + k);
        bf16x8 b1h = *(const bf16x8*)(Bhi + b1 + k);
        bf16x8 b1l = *(const bf16x8*)(Blo + b1 + k);
        acc00 = __builtin_amdgcn_mfma_f32_16x16x32_bf16(a0h, b0h, acc00, 0, 0, 0);
        acc01 = __builtin_amdgcn_mfma_f32_16x16x32_bf16(a0h, b1h, acc01, 0, 0, 0);
        acc10 = __builtin_amdgcn_mfma_f32_16x16x32_bf16(a1h, b0h, acc10, 0, 0, 0);
        acc11 = __builtin_amdgcn_mfma_f32_16x16x32_bf16(a1h, b1h, acc11, 0, 0, 0);
        acc00 = __builtin_amdgcn_mfma_f32_16x16x32_bf16(a0h, b0l, acc00, 0, 0, 0);
        acc01 = __builtin_amdgcn_mfma_f32_16x16x32_bf16(a0h, b1l, acc01, 0, 0, 0);
        acc10 = __builtin_amdgcn_mfma_f32_16x16x32_bf16(a1h, b0l, acc10, 0, 0, 0);
        acc11 = __builtin_amdgcn_mfma_f32_16x16x32_bf16(a1h, b1l, acc11, 0, 0, 0);
        acc00 = __builtin_amdgcn_mfma_f32_16x16x32_bf16(a0l, b0h, acc00, 0, 0, 0);
        acc01 = __builtin_amdgcn_mfma_f32_16x16x32_bf16(a0l, b1h, acc01, 0, 0, 0);
        acc10 = __builtin_amdgcn_mfma_f32_16x16x32_bf16(a1l, b0h, acc10, 0, 0, 0);
        acc11 = __builtin_amdgcn_mfma_f32_16x16x32_bf16(a1l, b1h, acc11, 0, 0, 0);
    }
    const int orow = (lane >> 4) * 4;
    #pragma unroll
    for (int j = 0; j < 4; ++j) {
        C[(size_t)(bm + orow + j) * Nc + bn + rl]           = acc00[j];
        C[(size_t)(bm + orow + j) * Nc + bn + 16 + rl]      = acc01[j];
        C[(size_t)(bm + 16 + orow + j) * Nc + bn + rl]      = acc10[j];
        C[(size_t)(bm + 16 + orow + j) * Nc + bn + 16 + rl] = acc11[j];
    }
}

// ---- s[h][i] = Wh[i, h*NH ..] . a1[h], d likewise. One wave per row. ----
template<int H>
__global__ void sd_kernel(const float* __restrict__ Wh, const float* __restrict__ a1,
                          const float* __restrict__ a2, float* __restrict__ s,
                          float* __restrict__ d, int N) {
    constexpr int NH = 512 / H;
    constexpr int G = NH / 8;           // lanes per head group (8 or 64)
    const int wid = threadIdx.x >> 6, lane = threadIdx.x & 63;
    const int row = blockIdx.x * 4 + wid;
    const float4* wr = (const float4*)(Wh + (size_t)row * 512);
    float4 wa = wr[lane * 2], wb = wr[lane * 2 + 1];
    const int h = lane / G;
    const int kb = (lane % G) * 8;
    const float* A1 = a1 + h * NH;
    const float* A2 = a2 + h * NH;
    float w0[8] = {wa.x, wa.y, wa.z, wa.w, wb.x, wb.y, wb.z, wb.w};
    float ps = 0.f, pd = 0.f;
    #pragma unroll
    for (int i = 0; i < 8; ++i) { ps += w0[i] * A1[kb + i]; pd += w0[i] * A2[kb + i]; }
    #pragma unroll
    for (int off = 1; off < G; off <<= 1) {
        ps += __shfl_xor(ps, off);
        pd += __shfl_xor(pd, off);
    }
    if ((lane % G) == 0) { s[h * N + row] = ps; d[h * N + row] = pd; }
}

// ---- neighbor extraction: adj row -> compact u16 index list (runs ONCE) ----
__global__ __launch_bounds__(256) void extract_nbrs(const float* __restrict__ adj,
        unsigned short* __restrict__ nbr, int* __restrict__ deg, int N) {
    __shared__ int wtot[4];
    __shared__ int wbase[4];
    const int t = threadIdx.x, lane = t & 63, wid = t >> 6, row = blockIdx.x;
    const float4* arow = (const float4*)(adj + (size_t)row * N);
    unsigned mask16 = 0;
    #pragma unroll
    for (int q = 0; q < 4; ++q) {
        float4 v = arow[t * 4 + q];
        if (v.x > 0.f) mask16 |= 1u << (q * 4 + 0);
        if (v.y > 0.f) mask16 |= 1u << (q * 4 + 1);
        if (v.z > 0.f) mask16 |= 1u << (q * 4 + 2);
        if (v.w > 0.f) mask16 |= 1u << (q * 4 + 3);
    }
    int cnt = __popc(mask16);
    int inc = cnt;
    #pragma unroll
    for (int off = 1; off < 64; off <<= 1) {
        int nv = __shfl_up(inc, off);
        if (lane >= off) inc += nv;
    }
    if (lane == 63) wtot[wid] = inc;
    __syncthreads();
    if (t == 0) {
        int b = 0;
        #pragma unroll
        for (int w = 0; w < 4; ++w) { wbase[w] = b; b += wtot[w]; }
        deg[row] = b;
    }
    __syncthreads();
    int base = wbase[wid] + inc - cnt;   // exclusive prefix
    unsigned short* dst = nbr + (size_t)row * 512 + base;
    int col0 = t * 16;
    int k = 0;
    while (mask16) {
        int b = __ffs(mask16) - 1;
        mask16 &= mask16 - 1;
        dst[k++] = (unsigned short)(col0 + b);
    }
}

// ---- attention + aggregate + ELU. One block (256 thr) per row, single pass. ----
// SPLIT: write hi/lo bf16 (feeds next MFMA GEMM); else write f32.
template<int H, bool SPLIT>
__global__ __launch_bounds__(256) void attn_kernel(
        const float* __restrict__ Wh, const float* __restrict__ s,
        const float* __restrict__ d, const unsigned short* __restrict__ nbr,
        const int* __restrict__ deg, float* __restrict__ out,
        unsigned short* __restrict__ ohi, unsigned short* __restrict__ olo, int N) {
    constexpr int F = 512, NH = F / H, CAP = 512, GS = 256 / H;
    __shared__ int nb[CAP];
    __shared__ float p[H][CAP];
    __shared__ float lred[H];
    __shared__ float red[4];
    const int t = threadIdx.x, lane = t & 63, row = blockIdx.x;
    const int M = deg[row];              // max realistic deg ~80 << CAP
    for (int j = t; j < M; j += 256) nb[j] = nbr[(size_t)row * 512 + j];
    __syncthreads();
    // head-parallel softmax: group of GS threads owns one head
    const int h = t / GS, sub = t % GS;
    const float sh = s[h * N + row];
    const float* dh = d + (size_t)h * N;
    float lm = -INFINITY;
    for (int j = sub; j < M; j += GS) {
        float e = sh + dh[nb[j]];
        e = e > 0.f ? e : 0.2f * e;      // leaky relu, slope 0.2
        p[h][j] = e;
        lm = fmaxf(lm, e);
    }
    if constexpr (GS <= 64) {
        #pragma unroll
        for (int off = GS / 2; off; off >>= 1) lm = fmaxf(lm, __shfl_xor(lm, off));
    } else {
        #pragma unroll
        for (int off = 32; off; off >>= 1) lm = fmaxf(lm, __shfl_xor(lm, off));
        if (lane == 0) red[t >> 6] = lm;
        __syncthreads();
        lm = fmaxf(fmaxf(red[0], red[1]), fmaxf(red[2], red[3]));
    }
    float ls = 0.f;
    for (int j = sub; j < M; j += GS) {
        float pe = expf(p[h][j] - lm);
        p[h][j] = pe;
        ls += pe;
    }
    if constexpr (GS <= 64) {
        #pragma unroll
        for (int off = GS / 2; off; off >>= 1) ls += __shfl_xor(ls, off);
    } else {
        #pragma unroll
        for (int off = 32; off; off >>= 1) ls += __shfl_xor(ls, off);
        __syncthreads();                 // red reuse
        if (lane == 0) red[t >> 6] = ls;
        __syncthreads();
        ls = red[0] + red[1] + red[2] + red[3];
    }
    if (sub == 0) lred[h] = ls;
    __syncthreads();
    // aggregate: thread owns contiguous cols 2t, 2t+1 (same head)
    const int c = 2 * t;
    const int hc = c / NH;
    const float inv = 1.f / lred[hc];
    const float* base = Wh + c;
    float ax = 0.f, ay = 0.f;
    #pragma unroll 4
    for (int j = 0; j < M; ++j) {
        float pw = p[hc][j];             // LDS broadcast within half-wave
        const float2 w = *(const float2*)(base + (size_t)nb[j] * F);
        ax += pw * w.x; ay += pw * w.y;
    }
    ax *= inv; ay *= inv;
    ax = ax > 0.f ? ax : expm1f(ax);     // ELU (alpha=1)
    ay = ay > 0.f ? ay : expm1f(ay);
    if constexpr (SPLIT) {
        unsigned short hx, lx, hy, ly;
        split2(ax, hx, lx); split2(ay, hy, ly);
        ushort2 hv, lv;
        hv.x = hx; hv.y = hy; lv.x = lx; lv.y = ly;
        *(ushort2*)(ohi + (size_t)row * F + c) = hv;
        *(ushort2*)(olo + (size_t)row * F + c) = lv;
    } else {
        float2 o; o.x = ax; o.y = ay;
        *(float2*)(out + (size_t)row * F + c) = o;
    }
}

extern "C" void kernel_launch(void* const* d_in, const int* in_sizes, int n_in,
                              void* d_out, int out_size, void* d_ws, size_t ws_size,
                              hipStream_t stream) {
    const float* x   = (const float*)d_in[0];
    // d_in[1] = left (unused by forward)
    const float* adj = (const float*)d_in[2];
    const float* Ws  = (const float*)d_in[3];
    const float* a1  = (const float*)d_in[4];
    const float* a2  = (const float*)d_in[5];
    const float* Wo  = (const float*)d_in[6];
    const float* ao1 = (const float*)d_in[7];
    const float* ao2 = (const float*)d_in[8];
    float* out = (float*)d_out;
    const int N = GN;

    float* ws   = (float*)d_ws;
    float* Wh   = ws;                    // 4096*512 f32
    float* Who  = Wh + 2097152;          // 4096*512 f32
    float* sbuf = Who + 2097152;         // 8*4096
    float* dbuf = sbuf + 32768;          // 8*4096
    float* sob  = dbuf + 32768;          // 4096
    float* dob  = sob + 4096;            // 4096
    unsigned short* nbrs = (unsigned short*)(dob + 4096);   // 4096*512 u16
    int*            deg  = (int*)(nbrs + 2097152);          // 4096 i32
    unsigned short* xhi  = (unsigned short*)(deg + 4096);   // 4096*512 u16
    unsigned short* xlo  = xhi + 2097152;
    unsigned short* hch  = xlo + 2097152;                   // hcat hi
    unsigned short* hcl  = hch + 2097152;                   // hcat lo
    unsigned short* wshi = hcl + 2097152;                   // 512*512
    unsigned short* wslo = wshi + 262144;
    unsigned short* wohi = wslo + 262144;
    unsigned short* wolo = wohi + 262144;
    // total ~38.3 MB

    hipLaunchKernelGGL(extract_nbrs, dim3(4096), dim3(256), 0, stream, adj, nbrs, deg, N);
    hipLaunchKernelGGL(pack_ws_split, dim3(1024), dim3(256), 0, stream, Ws, wshi, wslo);
    hipLaunchKernelGGL(pack_wo_split, dim3(1024), dim3(256), 0, stream, Wo, wohi, wolo);
    hipLaunchKernelGGL(split_f32, dim3(2048), dim3(256), 0, stream, x, xhi, xlo, 524288);
    hipLaunchKernelGGL(gemm_split, dim3(8, 64), dim3(256), 0, stream,
                       xhi, xlo, wshi, wslo, Wh, 4096, 512, 512);
    hipLaunchKernelGGL(sd_kernel<8>, dim3(1024), dim3(256), 0, stream, Wh, a1, a2, sbuf, dbuf, N);
    hipLaunchKernelGGL((attn_kernel<8, true>), dim3(4096), dim3(256), 0, stream,
                       Wh, sbuf, dbuf, nbrs, deg, (float*)nullptr, hch, hcl, N);
    hipLaunchKernelGGL(gemm_split, dim3(8, 64), dim3(256), 0, stream,
                       hch, hcl, wohi, wolo, Who, 4096, 512, 512);
    hipLaunchKernelGGL(sd_kernel<1>, dim3(1024), dim3(256), 0, stream, Who, ao1, ao2, sob, dob, N);
    hipLaunchKernelGGL((attn_kernel<1, false>), dim3(4096), dim3(256), 0, stream,
                       Who, sob, dob, nbrs, deg, out, (unsigned short*)nullptr,
                       (unsigned short*)nullptr, N);
}

// Round 5
// 114.892 us; speedup vs baseline: 1.8478x; 1.3706x over previous
//
#include <hip/hip_runtime.h>
#include <hip/hip_bf16.h>
#include <math.h>

// GAT forward, N=4096, F=512, H=8, NH=64.
// Round 5: fix prep grid (x-split needs 2048 blocks, had 512 -> 3/4 of x was
// poison). LDS-staged double-buffered MFMA GEMM (3-term bf16 split) unchanged.

#define GN 4096
#define GF 512

typedef __attribute__((ext_vector_type(8))) short bf16x8;
typedef __attribute__((ext_vector_type(4))) float f32x4;

__device__ inline unsigned short f2bf(float f) {
    unsigned u = __float_as_uint(f);
    return (unsigned short)((u + 0x7fffu + ((u >> 16) & 1u)) >> 16);
}
__device__ inline float bf2f(unsigned short h) {
    return __uint_as_float((unsigned)h << 16);
}
__device__ inline void split2(float v, unsigned short& h, unsigned short& l) {
    h = f2bf(v);
    l = f2bf(v - bf2f(h));
}
__device__ inline void gl16(const void* g, void* l) {
    __builtin_amdgcn_global_load_lds((const __attribute__((address_space(1))) unsigned int*)g,
                                     (__attribute__((address_space(3))) unsigned int*)l, 16, 0, 0);
}

// ---- fused prep: extract_nbrs + pack Ws^T + pack Wo^T + split x ----
// grid = 4096 + 1024 + 1024 + 2048 = 8192 blocks of 256
__global__ __launch_bounds__(256) void prep(
        const float* __restrict__ adj, const float* __restrict__ Ws,
        const float* __restrict__ Wo, const float* __restrict__ x,
        unsigned short* __restrict__ nbr, int* __restrict__ deg,
        unsigned short* __restrict__ wshi, unsigned short* __restrict__ wslo,
        unsigned short* __restrict__ wohi, unsigned short* __restrict__ wolo,
        unsigned short* __restrict__ xhi, unsigned short* __restrict__ xlo, int N) {
    __shared__ int wtot[4];
    __shared__ int wbase[4];
    int b = blockIdx.x;
    const int t = threadIdx.x;
    if (b < 4096) {                       // neighbor extraction, row = b
        const int lane = t & 63, wid = t >> 6, row = b;
        const float4* arow = (const float4*)(adj + (size_t)row * N);
        unsigned mask16 = 0;
        #pragma unroll
        for (int q = 0; q < 4; ++q) {
            float4 v = arow[t * 4 + q];
            if (v.x > 0.f) mask16 |= 1u << (q * 4 + 0);
            if (v.y > 0.f) mask16 |= 1u << (q * 4 + 1);
            if (v.z > 0.f) mask16 |= 1u << (q * 4 + 2);
            if (v.w > 0.f) mask16 |= 1u << (q * 4 + 3);
        }
        int cnt = __popc(mask16);
        int inc = cnt;
        #pragma unroll
        for (int off = 1; off < 64; off <<= 1) {
            int nv = __shfl_up(inc, off);
            if (lane >= off) inc += nv;
        }
        if (lane == 63) wtot[wid] = inc;
        __syncthreads();
        if (t == 0) {
            int s = 0;
            #pragma unroll
            for (int w = 0; w < 4; ++w) { wbase[w] = s; s += wtot[w]; }
            deg[row] = s;
        }
        __syncthreads();
        int base = wbase[wid] + inc - cnt;
        unsigned short* dst = nbr + (size_t)row * 512 + base;
        int col0 = t * 16;
        int k = 0;
        while (mask16) {
            int bi = __ffs(mask16) - 1;
            mask16 &= mask16 - 1;
            dst[k++] = (unsigned short)(col0 + bi);
        }
        return;
    }
    b -= 4096;
    if (b < 1024) {                       // Ws[H][F][NH] -> Bt[c][f] hi/lo
        int idx = b * 256 + t;
        int c = idx >> 9, f = idx & 511;
        int h = c >> 6, k = c & 63;
        float v = Ws[h * (512 * 64) + f * 64 + k];
        unsigned short hh, ll;
        split2(v, hh, ll);
        wshi[idx] = hh; wslo[idx] = ll;
        return;
    }
    b -= 1024;
    if (b < 1024) {                       // Wo[F][F] -> Bt[c][f] hi/lo
        int idx = b * 256 + t;
        int c = idx >> 9, f = idx & 511;
        float v = Wo[f * 512 + c];
        unsigned short hh, ll;
        split2(v, hh, ll);
        wohi[idx] = hh; wolo[idx] = ll;
        return;
    }
    b -= 1024;
    {                                     // split x -> hi/lo, 2048 blocks
        int i = b * 256 + t;              // i in [0, 524288)
        float4 v = ((const float4*)x)[i];
        ushort4 h, l;
        split2(v.x, h.x, l.x); split2(v.y, h.y, l.y);
        split2(v.z, h.z, l.z); split2(v.w, h.w, l.w);
        ((ushort4*)xhi)[i] = h;
        ((ushort4*)xlo)[i] = l;
    }
}

// ---- MFMA GEMM: C[M,Nc] = A[M,K] @ B[K,Nc]; A hi/lo [M][K], B hi/lo [Nc][K].
// 64x64 tile, BK=64, double-buffered LDS (8 tiles x 4KB x 2), 3-term split.
// LDS rows are 128B: XOR-swizzle chunk^(row&7), applied on the pre-swizzled
// global source (stage) and on ds_read (both-sides, rule #21).
__global__ __launch_bounds__(256) void gemm_3t(
        const unsigned short* __restrict__ Ahi, const unsigned short* __restrict__ Alo,
        const unsigned short* __restrict__ Bhi, const unsigned short* __restrict__ Blo,
        float* __restrict__ C, int M, int K, int Nc) {
    __shared__ char lds[65536];           // 2 buffers x 32KB (Ah|Al|Bh|Bl)
    const int t = threadIdx.x, lane = t & 63, wid = t >> 6;
    const int bm0 = blockIdx.y * 64, bn0 = blockIdx.x * 64;
    const int r0 = t >> 3;
    const int sc8 = (((t & 7) ^ ((t >> 3) & 7)) << 3);   // swizzled chunk, elems
    const size_t aoff = (size_t)(bm0 + r0) * K + sc8;
    const size_t boff = (size_t)(bn0 + r0) * K + sc8;
    const size_t half = (size_t)32 * K;

    auto stage = [&](char* dst, int k0) {
        gl16(Ahi + aoff + k0,        dst + 0 * 4096 + t * 16);
        gl16(Ahi + aoff + half + k0, dst + 1 * 4096 + t * 16);
        gl16(Alo + aoff + k0,        dst + 2 * 4096 + t * 16);
        gl16(Alo + aoff + half + k0, dst + 3 * 4096 + t * 16);
        gl16(Bhi + boff + k0,        dst + 4 * 4096 + t * 16);
        gl16(Bhi + boff + half + k0, dst + 5 * 4096 + t * 16);
        gl16(Blo + boff + k0,        dst + 6 * 4096 + t * 16);
        gl16(Blo + boff + half + k0, dst + 7 * 4096 + t * 16);
    };

    f32x4 acc00 = {0,0,0,0}, acc01 = {0,0,0,0}, acc10 = {0,0,0,0}, acc11 = {0,0,0,0};
    const int mq = (wid >> 1) * 32, nq = (wid & 1) * 32;
    const int rl = lane & 15, hl = lane >> 4;
    const int swz = rl & 7;               // (row&7) equal for row, row+16, row+32

    auto compute = [&](const char* Lb) {
        const char* Ah_ = Lb;
        const char* Al_ = Lb + 8192;
        const char* Bh_ = Lb + 16384;
        const char* Bl_ = Lb + 24576;
        #pragma unroll
        for (int s = 0; s < 2; ++s) {
            const int ch = ((s * 4 + hl) ^ swz) * 16;
            const int ra0 = (mq + rl) * 128, ra1 = ra0 + 16 * 128;
            const int rb0 = (nq + rl) * 128, rb1 = rb0 + 16 * 128;
            bf16x8 A0h = *(const bf16x8*)(Ah_ + ra0 + ch);
            bf16x8 A1h = *(const bf16x8*)(Ah_ + ra1 + ch);
            bf16x8 A0l = *(const bf16x8*)(Al_ + ra0 + ch);
            bf16x8 A1l = *(const bf16x8*)(Al_ + ra1 + ch);
            bf16x8 B0h = *(const bf16x8*)(Bh_ + rb0 + ch);
            bf16x8 B1h = *(const bf16x8*)(Bh_ + rb1 + ch);
            bf16x8 B0l = *(const bf16x8*)(Bl_ + rb0 + ch);
            bf16x8 B1l = *(const bf16x8*)(Bl_ + rb1 + ch);
            acc00 = __builtin_amdgcn_mfma_f32_16x16x32_bf16(A0h, B0h, acc00, 0, 0, 0);
            acc01 = __builtin_amdgcn_mfma_f32_16x16x32_bf16(A0h, B1h, acc01, 0, 0, 0);
            acc10 = __builtin_amdgcn_mfma_f32_16x16x32_bf16(A1h, B0h, acc10, 0, 0, 0);
            acc11 = __builtin_amdgcn_mfma_f32_16x16x32_bf16(A1h, B1h, acc11, 0, 0, 0);
            acc00 = __builtin_amdgcn_mfma_f32_16x16x32_bf16(A0h, B0l, acc00, 0, 0, 0);
            acc01 = __builtin_amdgcn_mfma_f32_16x16x32_bf16(A0h, B1l, acc01, 0, 0, 0);
            acc10 = __builtin_amdgcn_mfma_f32_16x16x32_bf16(A1h, B0l, acc10, 0, 0, 0);
            acc11 = __builtin_amdgcn_mfma_f32_16x16x32_bf16(A1h, B1l, acc11, 0, 0, 0);
            acc00 = __builtin_amdgcn_mfma_f32_16x16x32_bf16(A0l, B0h, acc00, 0, 0, 0);
            acc01 = __builtin_amdgcn_mfma_f32_16x16x32_bf16(A0l, B1h, acc01, 0, 0, 0);
            acc10 = __builtin_amdgcn_mfma_f32_16x16x32_bf16(A1l, B0h, acc10, 0, 0, 0);
            acc11 = __builtin_amdgcn_mfma_f32_16x16x32_bf16(A1l, B1h, acc11, 0, 0, 0);
        }
    };

    stage(lds, 0);
    __syncthreads();
    const int NT = K / 64;                // 8 steps
    for (int st = 0; st < NT; ++st) {
        char* cur = lds + (st & 1) * 32768;
        if (st + 1 < NT) stage(lds + ((st + 1) & 1) * 32768, (st + 1) * 64);
        compute(cur);
        __syncthreads();
    }

    const int orow = hl * 4;
    #pragma unroll
    for (int j = 0; j < 4; ++j) {
        C[(size_t)(bm0 + mq + orow + j) * Nc + bn0 + nq + rl]           = acc00[j];
        C[(size_t)(bm0 + mq + orow + j) * Nc + bn0 + nq + 16 + rl]      = acc01[j];
        C[(size_t)(bm0 + mq + 16 + orow + j) * Nc + bn0 + nq + rl]      = acc10[j];
        C[(size_t)(bm0 + mq + 16 + orow + j) * Nc + bn0 + nq + 16 + rl] = acc11[j];
    }
}

// ---- s[h][i] = Wh[i, h*NH ..] . a1[h], d likewise. One wave per row. ----
template<int H>
__global__ void sd_kernel(const float* __restrict__ Wh, const float* __restrict__ a1,
                          const float* __restrict__ a2, float* __restrict__ s,
                          float* __restrict__ d, int N) {
    constexpr int NH = 512 / H;
    constexpr int G = NH / 8;           // lanes per head group (8 or 64)
    const int wid = threadIdx.x >> 6, lane = threadIdx.x & 63;
    const int row = blockIdx.x * 4 + wid;
    const float4* wr = (const float4*)(Wh + (size_t)row * 512);
    float4 wa = wr[lane * 2], wb = wr[lane * 2 + 1];
    const int h = lane / G;
    const int kb = (lane % G) * 8;
    const float* A1 = a1 + h * NH;
    const float* A2 = a2 + h * NH;
    float w0[8] = {wa.x, wa.y, wa.z, wa.w, wb.x, wb.y, wb.z, wb.w};
    float ps = 0.f, pd = 0.f;
    #pragma unroll
    for (int i = 0; i < 8; ++i) { ps += w0[i] * A1[kb + i]; pd += w0[i] * A2[kb + i]; }
    #pragma unroll
    for (int off = 1; off < G; off <<= 1) {
        ps += __shfl_xor(ps, off);
        pd += __shfl_xor(pd, off);
    }
    if ((lane % G) == 0) { s[h * N + row] = ps; d[h * N + row] = pd; }
}

// ---- attention + aggregate + ELU. One block (256 thr) per row, single pass. ----
// SPLIT: also write hi/lo bf16 (feeds next MFMA GEMM); else write f32.
template<int H, bool SPLIT>
__global__ __launch_bounds__(256) void attn_kernel(
        const float* __restrict__ Wh, const float* __restrict__ s,
        const float* __restrict__ d, const unsigned short* __restrict__ nbr,
        const int* __restrict__ deg, float* __restrict__ out,
        unsigned short* __restrict__ ohi, unsigned short* __restrict__ olo, int N) {
    constexpr int F = 512, NH = F / H, CAP = 512, GS = 256 / H;
    __shared__ int nb[CAP];
    __shared__ float p[H][CAP];
    __shared__ float lred[H];
    __shared__ float red[4];
    const int t = threadIdx.x, lane = t & 63, row = blockIdx.x;
    const int M = deg[row];
    for (int j = t; j < M; j += 256) nb[j] = nbr[(size_t)row * 512 + j];
    __syncthreads();
    const int h = t / GS, sub = t % GS;
    const float sh = s[h * N + row];
    const float* dh = d + (size_t)h * N;
    float lm = -INFINITY;
    for (int j = sub; j < M; j += GS) {
        float e = sh + dh[nb[j]];
        e = e > 0.f ? e : 0.2f * e;
        p[h][j] = e;
        lm = fmaxf(lm, e);
    }
    if constexpr (GS <= 64) {
        #pragma unroll
        for (int off = GS / 2; off; off >>= 1) lm = fmaxf(lm, __shfl_xor(lm, off));
    } else {
        #pragma unroll
        for (int off = 32; off; off >>= 1) lm = fmaxf(lm, __shfl_xor(lm, off));
        if (lane == 0) red[t >> 6] = lm;
        __syncthreads();
        lm = fmaxf(fmaxf(red[0], red[1]), fmaxf(red[2], red[3]));
    }
    float ls = 0.f;
    for (int j = sub; j < M; j += GS) {
        float pe = expf(p[h][j] - lm);
        p[h][j] = pe;
        ls += pe;
    }
    if constexpr (GS <= 64) {
        #pragma unroll
        for (int off = GS / 2; off; off >>= 1) ls += __shfl_xor(ls, off);
    } else {
        #pragma unroll
        for (int off = 32; off; off >>= 1) ls += __shfl_xor(ls, off);
        __syncthreads();
        if (lane == 0) red[t >> 6] = ls;
        __syncthreads();
        ls = red[0] + red[1] + red[2] + red[3];
    }
    if (sub == 0) lred[h] = ls;
    __syncthreads();
    const int c = 2 * t;
    const int hc = c / NH;
    const float inv = 1.f / lred[hc];
    const float* base = Wh + c;
    float ax = 0.f, ay = 0.f;
    #pragma unroll 4
    for (int j = 0; j < M; ++j) {
        float pw = p[hc][j];
        const float2 w = *(const float2*)(base + (size_t)nb[j] * F);
        ax += pw * w.x; ay += pw * w.y;
    }
    ax *= inv; ay *= inv;
    ax = ax > 0.f ? ax : expm1f(ax);
    ay = ay > 0.f ? ay : expm1f(ay);
    if constexpr (SPLIT) {
        unsigned short hx, lx, hy, ly;
        split2(ax, hx, lx); split2(ay, hy, ly);
        ushort2 hv, lv;
        hv.x = hx; hv.y = hy; lv.x = lx; lv.y = ly;
        *(ushort2*)(ohi + (size_t)row * F + c) = hv;
        *(ushort2*)(olo + (size_t)row * F + c) = lv;
    } else {
        float2 o; o.x = ax; o.y = ay;
        *(float2*)(out + (size_t)row * F + c) = o;
    }
}

extern "C" void kernel_launch(void* const* d_in, const int* in_sizes, int n_in,
                              void* d_out, int out_size, void* d_ws, size_t ws_size,
                              hipStream_t stream) {
    const float* x   = (const float*)d_in[0];
    const float* adj = (const float*)d_in[2];
    const float* Ws  = (const float*)d_in[3];
    const float* a1  = (const float*)d_in[4];
    const float* a2  = (const float*)d_in[5];
    const float* Wo  = (const float*)d_in[6];
    const float* ao1 = (const float*)d_in[7];
    const float* ao2 = (const float*)d_in[8];
    float* out = (float*)d_out;
    const int N = GN;

    float* ws   = (float*)d_ws;
    float* Wh   = ws;                    // 4096*512 f32
    float* Who  = Wh + 2097152;          // 4096*512 f32
    float* sbuf = Who + 2097152;         // 8*4096
    float* dbuf = sbuf + 32768;          // 8*4096
    float* sob  = dbuf + 32768;          // 4096
    float* dob  = sob + 4096;            // 4096
    unsigned short* nbrs = (unsigned short*)(dob + 4096);   // 4096*512 u16
    int*            deg  = (int*)(nbrs + 2097152);          // 4096 i32
    unsigned short* xhi  = (unsigned short*)(deg + 4096);   // 4096*512 u16
    unsigned short* xlo  = xhi + 2097152;
    unsigned short* hch  = xlo + 2097152;                   // hcat hi
    unsigned short* hcl  = hch + 2097152;                   // hcat lo
    unsigned short* wshi = hcl + 2097152;                   // 512*512
    unsigned short* wslo = wshi + 262144;
    unsigned short* wohi = wslo + 262144;
    unsigned short* wolo = wohi + 262144;

    hipLaunchKernelGGL(prep, dim3(8192), dim3(256), 0, stream,
                       adj, Ws, Wo, x, nbrs, deg, wshi, wslo, wohi, wolo, xhi, xlo, N);
    hipLaunchKernelGGL(gemm_3t, dim3(8, 64), dim3(256), 0, stream,
                       xhi, xlo, wshi, wslo, Wh, 4096, 512, 512);
    hipLaunchKernelGGL(sd_kernel<8>, dim3(1024), dim3(256), 0, stream, Wh, a1, a2, sbuf, dbuf, N);
    hipLaunchKernelGGL((attn_kernel<8, true>), dim3(4096), dim3(256), 0, stream,
                       Wh, sbuf, dbuf, nbrs, deg, (float*)nullptr, hch, hcl, N);
    hipLaunchKernelGGL(gemm_3t, dim3(8, 64), dim3(256), 0, stream,
                       hch, hcl, wohi, wolo, Who, 4096, 512, 512);
    hipLaunchKernelGGL(sd_kernel<1>, dim3(1024), dim3(256), 0, stream, Who, ao1, ao2, sob, dob, N);
    hipLaunchKernelGGL((attn_kernel<1, false>), dim3(4096), dim3(256), 0, stream,
                       Who, sob, dob, nbrs, deg, out, (unsigned short*)nullptr,
                       (unsigned short*)nullptr, N);
}

// Round 6
// 112.322 us; speedup vs baseline: 1.8901x; 1.0229x over previous
//
#include <hip/hip_runtime.h>
#include <hip/hip_bf16.h>
#include <math.h>

// GAT forward, N=4096, F=512, H=8, NH=64.
// Round 6: fuse s/d dot-products into GEMM epilogues (layer1 exact per-head,
// layer2 via deterministic per-bn partials summed in attn), LDS-transposed
// weight packs in prep, 5 launches total.

#define GN 4096
#define GF 512

typedef __attribute__((ext_vector_type(8))) short bf16x8;
typedef __attribute__((ext_vector_type(4))) float f32x4;

__device__ inline unsigned short f2bf(float f) {
    unsigned u = __float_as_uint(f);
    return (unsigned short)((u + 0x7fffu + ((u >> 16) & 1u)) >> 16);
}
__device__ inline float bf2f(unsigned short h) {
    return __uint_as_float((unsigned)h << 16);
}
__device__ inline void split2(float v, unsigned short& h, unsigned short& l) {
    h = f2bf(v);
    l = f2bf(v - bf2f(h));
}
__device__ inline void gl16(const void* g, void* l) {
    __builtin_amdgcn_global_load_lds((const __attribute__((address_space(1))) unsigned int*)g,
                                     (__attribute__((address_space(3))) unsigned int*)l, 16, 0, 0);
}

// ---- fused prep: extract_nbrs + LDS-transposed packs of Ws/Wo + split x ----
// grid = 4096 (extract) + 64 (Ws) + 64 (Wo) + 2048 (x split) = 6272
__global__ __launch_bounds__(256) void prep(
        const float* __restrict__ adj, const float* __restrict__ Ws,
        const float* __restrict__ Wo, const float* __restrict__ x,
        unsigned short* __restrict__ nbr, int* __restrict__ deg,
        unsigned short* __restrict__ wshi, unsigned short* __restrict__ wslo,
        unsigned short* __restrict__ wohi, unsigned short* __restrict__ wolo,
        unsigned short* __restrict__ xhi, unsigned short* __restrict__ xlo, int N) {
    __shared__ int wtot[4];
    __shared__ int wbase[4];
    __shared__ float T[64][65];
    int b = blockIdx.x;
    const int t = threadIdx.x;
    if (b < 4096) {                       // neighbor extraction, row = b
        const int lane = t & 63, wid = t >> 6, row = b;
        const float4* arow = (const float4*)(adj + (size_t)row * N);
        unsigned mask16 = 0;
        #pragma unroll
        for (int q = 0; q < 4; ++q) {
            float4 v = arow[t * 4 + q];
            if (v.x > 0.f) mask16 |= 1u << (q * 4 + 0);
            if (v.y > 0.f) mask16 |= 1u << (q * 4 + 1);
            if (v.z > 0.f) mask16 |= 1u << (q * 4 + 2);
            if (v.w > 0.f) mask16 |= 1u << (q * 4 + 3);
        }
        int cnt = __popc(mask16);
        int inc = cnt;
        #pragma unroll
        for (int off = 1; off < 64; off <<= 1) {
            int nv = __shfl_up(inc, off);
            if (lane >= off) inc += nv;
        }
        if (lane == 63) wtot[wid] = inc;
        __syncthreads();
        if (t == 0) {
            int s = 0;
            #pragma unroll
            for (int w = 0; w < 4; ++w) { wbase[w] = s; s += wtot[w]; }
            deg[row] = s;
        }
        __syncthreads();
        int base = wbase[wid] + inc - cnt;
        unsigned short* dst = nbr + (size_t)row * 512 + base;
        int col0 = t * 16;
        int k = 0;
        while (mask16) {
            int bi = __ffs(mask16) - 1;
            mask16 &= mask16 - 1;
            dst[k++] = (unsigned short)(col0 + bi);
        }
        return;
    }
    b -= 4096;
    if (b < 64) {                         // Ws[h][f][k] -> Bt[h*64+k][f], tiled
        const int h = b >> 3, f0 = (b & 7) * 64;
        #pragma unroll
        for (int i = 0; i < 16; ++i) {
            int idx = i * 256 + t;
            int fr = idx >> 6, k = idx & 63;
            T[fr][k] = Ws[h * 32768 + (f0 + fr) * 64 + k];
        }
        __syncthreads();
        #pragma unroll
        for (int i = 0; i < 16; ++i) {
            int idx = i * 256 + t;
            int k = idx >> 6, fr = idx & 63;
            unsigned short hh, ll;
            split2(T[fr][k], hh, ll);
            size_t dst = (size_t)(h * 64 + k) * 512 + f0 + fr;
            wshi[dst] = hh; wslo[dst] = ll;
        }
        return;
    }
    b -= 64;
    if (b < 64) {                         // Wo[f][c] -> Bt[c][f], tiled
        const int c0 = (b >> 3) * 64, f0 = (b & 7) * 64;
        #pragma unroll
        for (int i = 0; i < 16; ++i) {
            int idx = i * 256 + t;
            int fr = idx >> 6, k = idx & 63;
            T[fr][k] = Wo[(size_t)(f0 + fr) * 512 + c0 + k];
        }
        __syncthreads();
        #pragma unroll
        for (int i = 0; i < 16; ++i) {
            int idx = i * 256 + t;
            int k = idx >> 6, fr = idx & 63;
            unsigned short hh, ll;
            split2(T[fr][k], hh, ll);
            size_t dst = (size_t)(c0 + k) * 512 + f0 + fr;
            wohi[dst] = hh; wolo[dst] = ll;
        }
        return;
    }
    b -= 64;
    {                                     // split x -> hi/lo, 2048 blocks
        int i = b * 256 + t;              // [0, 524288)
        float4 v = ((const float4*)x)[i];
        ushort4 h, l;
        split2(v.x, h.x, l.x); split2(v.y, h.y, l.y);
        split2(v.z, h.z, l.z); split2(v.w, h.w, l.w);
        ((ushort4*)xhi)[i] = h;
        ((ushort4*)xlo)[i] = l;
    }
}

// ---- MFMA GEMM + fused s/d epilogue.
// C[M,Nc] = A[M,K] @ B[K,Nc]; A hi/lo [M][K], B hi/lo [Nc][K].
// 64x64 tile, BK=64, double-buffered LDS, 3-term bf16 split.
// Epilogue: per-row dots with a1v/a2v over this block's 64 cols.
//   PART=false: block's cols = one full head -> write s/d[blockIdx.x*M + row].
//   PART=true:  64-col partial -> write spart/dpart[row*8 + blockIdx.x].
template<bool PART>
__global__ __launch_bounds__(256) void gemm_3t(
        const unsigned short* __restrict__ Ahi, const unsigned short* __restrict__ Alo,
        const unsigned short* __restrict__ Bhi, const unsigned short* __restrict__ Blo,
        const float* __restrict__ a1v, const float* __restrict__ a2v,
        float* __restrict__ C, float* __restrict__ sdst, float* __restrict__ ddst,
        int M, int K, int Nc) {
    __shared__ char lds[65536];           // 2 buffers x 32KB (Ah|Al|Bh|Bl)
    const int t = threadIdx.x, lane = t & 63, wid = t >> 6;
    const int bm0 = blockIdx.y * 64, bn0 = blockIdx.x * 64;
    const int r0 = t >> 3;
    const int sc8 = (((t & 7) ^ ((t >> 3) & 7)) << 3);   // swizzled chunk, elems
    const size_t aoff = (size_t)(bm0 + r0) * K + sc8;
    const size_t boff = (size_t)(bn0 + r0) * K + sc8;
    const size_t half = (size_t)32 * K;

    auto stage = [&](char* dst, int k0) {
        gl16(Ahi + aoff + k0,        dst + 0 * 4096 + t * 16);
        gl16(Ahi + aoff + half + k0, dst + 1 * 4096 + t * 16);
        gl16(Alo + aoff + k0,        dst + 2 * 4096 + t * 16);
        gl16(Alo + aoff + half + k0, dst + 3 * 4096 + t * 16);
        gl16(Bhi + boff + k0,        dst + 4 * 4096 + t * 16);
        gl16(Bhi + boff + half + k0, dst + 5 * 4096 + t * 16);
        gl16(Blo + boff + k0,        dst + 6 * 4096 + t * 16);
        gl16(Blo + boff + half + k0, dst + 7 * 4096 + t * 16);
    };

    f32x4 acc00 = {0,0,0,0}, acc01 = {0,0,0,0}, acc10 = {0,0,0,0}, acc11 = {0,0,0,0};
    const int mq = (wid >> 1) * 32, nq = (wid & 1) * 32;
    const int rl = lane & 15, hl = lane >> 4;
    const int swz = rl & 7;

    auto compute = [&](const char* Lb) {
        const char* Ah_ = Lb;
        const char* Al_ = Lb + 8192;
        const char* Bh_ = Lb + 16384;
        const char* Bl_ = Lb + 24576;
        #pragma unroll
        for (int s = 0; s < 2; ++s) {
            const int ch = ((s * 4 + hl) ^ swz) * 16;
            const int ra0 = (mq + rl) * 128, ra1 = ra0 + 16 * 128;
            const int rb0 = (nq + rl) * 128, rb1 = rb0 + 16 * 128;
            bf16x8 A0h = *(const bf16x8*)(Ah_ + ra0 + ch);
            bf16x8 A1h = *(const bf16x8*)(Ah_ + ra1 + ch);
            bf16x8 A0l = *(const bf16x8*)(Al_ + ra0 + ch);
            bf16x8 A1l = *(const bf16x8*)(Al_ + ra1 + ch);
            bf16x8 B0h = *(const bf16x8*)(Bh_ + rb0 + ch);
            bf16x8 B1h = *(const bf16x8*)(Bh_ + rb1 + ch);
            bf16x8 B0l = *(const bf16x8*)(Bl_ + rb0 + ch);
            bf16x8 B1l = *(const bf16x8*)(Bl_ + rb1 + ch);
            acc00 = __builtin_amdgcn_mfma_f32_16x16x32_bf16(A0h, B0h, acc00, 0, 0, 0);
            acc01 = __builtin_amdgcn_mfma_f32_16x16x32_bf16(A0h, B1h, acc01, 0, 0, 0);
            acc10 = __builtin_amdgcn_mfma_f32_16x16x32_bf16(A1h, B0h, acc10, 0, 0, 0);
            acc11 = __builtin_amdgcn_mfma_f32_16x16x32_bf16(A1h, B1h, acc11, 0, 0, 0);
            acc00 = __builtin_amdgcn_mfma_f32_16x16x32_bf16(A0h, B0l, acc00, 0, 0, 0);
            acc01 = __builtin_amdgcn_mfma_f32_16x16x32_bf16(A0h, B1l, acc01, 0, 0, 0);
            acc10 = __builtin_amdgcn_mfma_f32_16x16x32_bf16(A1h, B0l, acc10, 0, 0, 0);
            acc11 = __builtin_amdgcn_mfma_f32_16x16x32_bf16(A1h, B1l, acc11, 0, 0, 0);
            acc00 = __builtin_amdgcn_mfma_f32_16x16x32_bf16(A0l, B0h, acc00, 0, 0, 0);
            acc01 = __builtin_amdgcn_mfma_f32_16x16x32_bf16(A0l, B1h, acc01, 0, 0, 0);
            acc10 = __builtin_amdgcn_mfma_f32_16x16x32_bf16(A1l, B0h, acc10, 0, 0, 0);
            acc11 = __builtin_amdgcn_mfma_f32_16x16x32_bf16(A1l, B1h, acc11, 0, 0, 0);
        }
    };

    stage(lds, 0);
    __syncthreads();
    const int NT = K / 64;                // 8 steps
    for (int st = 0; st < NT; ++st) {
        char* cur = lds + (st & 1) * 32768;
        if (st + 1 < NT) stage(lds + ((st + 1) & 1) * 32768, (st + 1) * 64);
        compute(cur);
        __syncthreads();
    }

    const int orow = hl * 4;
    #pragma unroll
    for (int j = 0; j < 4; ++j) {
        C[(size_t)(bm0 + mq + orow + j) * Nc + bn0 + nq + rl]           = acc00[j];
        C[(size_t)(bm0 + mq + orow + j) * Nc + bn0 + nq + 16 + rl]      = acc01[j];
        C[(size_t)(bm0 + mq + 16 + orow + j) * Nc + bn0 + nq + rl]      = acc10[j];
        C[(size_t)(bm0 + mq + 16 + orow + j) * Nc + bn0 + nq + 16 + rl] = acc11[j];
    }

    // ---- fused s/d epilogue (exact fp32, same acc values) ----
    const int C0 = bn0 + nq + rl, C1 = C0 + 16;
    const float a1c0 = a1v[C0], a1c1 = a1v[C1];
    const float a2c0 = a2v[C0], a2c1 = a2v[C1];
    float ps0[4], ps1[4], pd0[4], pd1[4];
    #pragma unroll
    for (int j = 0; j < 4; ++j) {
        ps0[j] = acc00[j] * a1c0 + acc01[j] * a1c1;
        ps1[j] = acc10[j] * a1c0 + acc11[j] * a1c1;
        pd0[j] = acc00[j] * a2c0 + acc01[j] * a2c1;
        pd1[j] = acc10[j] * a2c0 + acc11[j] * a2c1;
    }
    #pragma unroll
    for (int off = 1; off < 16; off <<= 1) {
        #pragma unroll
        for (int j = 0; j < 4; ++j) {
            ps0[j] += __shfl_xor(ps0[j], off);
            ps1[j] += __shfl_xor(ps1[j], off);
            pd0[j] += __shfl_xor(pd0[j], off);
            pd1[j] += __shfl_xor(pd1[j], off);
        }
    }
    float* eps = (float*)lds;             // [0:64) s, [64:128) d (rows in tile)
    if ((wid & 1) == 0 && rl == 0) {
        #pragma unroll
        for (int j = 0; j < 4; ++j) {
            eps[mq + orow + j]           = ps0[j];
            eps[mq + 16 + orow + j]      = ps1[j];
            eps[64 + mq + orow + j]      = pd0[j];
            eps[64 + mq + 16 + orow + j] = pd1[j];
        }
    }
    __syncthreads();
    if ((wid & 1) == 1 && rl == 0) {
        #pragma unroll
        for (int j = 0; j < 4; ++j) {
            const int t0 = mq + orow + j, t1 = t0 + 16;
            const float vs0 = ps0[j] + eps[t0];
            const float vs1 = ps1[j] + eps[t1];
            const float vd0 = pd0[j] + eps[64 + t0];
            const float vd1 = pd1[j] + eps[64 + t1];
            if constexpr (PART) {
                sdst[(size_t)(bm0 + t0) * 8 + blockIdx.x] = vs0;
                sdst[(size_t)(bm0 + t1) * 8 + blockIdx.x] = vs1;
                ddst[(size_t)(bm0 + t0) * 8 + blockIdx.x] = vd0;
                ddst[(size_t)(bm0 + t1) * 8 + blockIdx.x] = vd1;
            } else {
                float* sh_ = sdst + (size_t)blockIdx.x * M;
                float* dh_ = ddst + (size_t)blockIdx.x * M;
                sh_[bm0 + t0] = vs0; sh_[bm0 + t1] = vs1;
                dh_[bm0 + t0] = vd0; dh_[bm0 + t1] = vd1;
            }
        }
    }
}

// ---- attention + aggregate + ELU. One block (256 thr) per row, single pass. ----
// SPLIT: also write hi/lo bf16 (feeds next MFMA GEMM); else write f32.
// PART8: s/d are [row][8] per-bn partials (layer 2); else s/d are [H][N].
template<int H, bool SPLIT, bool PART8>
__global__ __launch_bounds__(256) void attn_kernel(
        const float* __restrict__ Wh, const float* __restrict__ s,
        const float* __restrict__ d, const unsigned short* __restrict__ nbr,
        const int* __restrict__ deg, float* __restrict__ out,
        unsigned short* __restrict__ ohi, unsigned short* __restrict__ olo, int N) {
    constexpr int F = 512, NH = F / H, CAP = 512, GS = 256 / H;
    __shared__ int nb[CAP];
    __shared__ float p[H][CAP];
    __shared__ float lred[H];
    __shared__ float red[4];
    const int t = threadIdx.x, lane = t & 63, row = blockIdx.x;
    const int M = deg[row];
    for (int j = t; j < M; j += 256) nb[j] = nbr[(size_t)row * 512 + j];
    __syncthreads();
    const int h = t / GS, sub = t % GS;
    float sh;
    if constexpr (PART8) {
        const float4* sp = (const float4*)(s + (size_t)row * 8);
        float4 s0 = sp[0], s1 = sp[1];
        sh = ((s0.x + s0.y) + (s0.z + s0.w)) + ((s1.x + s1.y) + (s1.z + s1.w));
    } else {
        sh = s[h * N + row];
    }
    float lm = -INFINITY;
    for (int j = sub; j < M; j += GS) {
        float dv;
        if constexpr (PART8) {
            const float4* dp = (const float4*)(d + (size_t)nb[j] * 8);
            float4 d0 = dp[0], d1 = dp[1];
            dv = ((d0.x + d0.y) + (d0.z + d0.w)) + ((d1.x + d1.y) + (d1.z + d1.w));
        } else {
            dv = d[h * N + nb[j]];
        }
        float e = sh + dv;
        e = e > 0.f ? e : 0.2f * e;
        p[h][j] = e;
        lm = fmaxf(lm, e);
    }
    if constexpr (GS <= 64) {
        #pragma unroll
        for (int off = GS / 2; off; off >>= 1) lm = fmaxf(lm, __shfl_xor(lm, off));
    } else {
        #pragma unroll
        for (int off = 32; off; off >>= 1) lm = fmaxf(lm, __shfl_xor(lm, off));
        if (lane == 0) red[t >> 6] = lm;
        __syncthreads();
        lm = fmaxf(fmaxf(red[0], red[1]), fmaxf(red[2], red[3]));
    }
    float ls = 0.f;
    for (int j = sub; j < M; j += GS) {
        float pe = expf(p[h][j] - lm);
        p[h][j] = pe;
        ls += pe;
    }
    if constexpr (GS <= 64) {
        #pragma unroll
        for (int off = GS / 2; off; off >>= 1) ls += __shfl_xor(ls, off);
    } else {
        #pragma unroll
        for (int off = 32; off; off >>= 1) ls += __shfl_xor(ls, off);
        __syncthreads();
        if (lane == 0) red[t >> 6] = ls;
        __syncthreads();
        ls = red[0] + red[1] + red[2] + red[3];
    }
    if (sub == 0) lred[h] = ls;
    __syncthreads();
    const int c = 2 * t;
    const int hc = c / NH;
    const float inv = 1.f / lred[hc];
    const float* base = Wh + c;
    float ax = 0.f, ay = 0.f;
    #pragma unroll 4
    for (int j = 0; j < M; ++j) {
        float pw = p[hc][j];
        const float2 w = *(const float2*)(base + (size_t)nb[j] * F);
        ax += pw * w.x; ay += pw * w.y;
    }
    ax *= inv; ay *= inv;
    ax = ax > 0.f ? ax : expm1f(ax);
    ay = ay > 0.f ? ay : expm1f(ay);
    if constexpr (SPLIT) {
        unsigned short hx, lx, hy, ly;
        split2(ax, hx, lx); split2(ay, hy, ly);
        ushort2 hv, lv;
        hv.x = hx; hv.y = hy; lv.x = lx; lv.y = ly;
        *(ushort2*)(ohi + (size_t)row * F + c) = hv;
        *(ushort2*)(olo + (size_t)row * F + c) = lv;
    } else {
        float2 o; o.x = ax; o.y = ay;
        *(float2*)(out + (size_t)row * F + c) = o;
    }
}

extern "C" void kernel_launch(void* const* d_in, const int* in_sizes, int n_in,
                              void* d_out, int out_size, void* d_ws, size_t ws_size,
                              hipStream_t stream) {
    const float* x   = (const float*)d_in[0];
    const float* adj = (const float*)d_in[2];
    const float* Ws  = (const float*)d_in[3];
    const float* a1  = (const float*)d_in[4];   // [H][64] flat = [512], c=h*64+k
    const float* a2  = (const float*)d_in[5];
    const float* Wo  = (const float*)d_in[6];
    const float* ao1 = (const float*)d_in[7];   // [512]
    const float* ao2 = (const float*)d_in[8];
    float* out = (float*)d_out;
    const int N = GN;

    float* ws    = (float*)d_ws;
    float* Wh    = ws;                    // 4096*512 f32
    float* Who   = Wh + 2097152;          // 4096*512 f32
    float* sbuf  = Who + 2097152;         // 8*4096
    float* dbuf  = sbuf + 32768;          // 8*4096
    float* spart = dbuf + 32768;          // 4096*8
    float* dpart = spart + 32768;         // 4096*8
    unsigned short* nbrs = (unsigned short*)(dpart + 32768); // 4096*512 u16
    int*            deg  = (int*)(nbrs + 2097152);           // 4096 i32
    unsigned short* xhi  = (unsigned short*)(deg + 4096);    // 4096*512 u16
    unsigned short* xlo  = xhi + 2097152;
    unsigned short* hch  = xlo + 2097152;                    // hcat hi
    unsigned short* hcl  = hch + 2097152;                    // hcat lo
    unsigned short* wshi = hcl + 2097152;                    // 512*512
    unsigned short* wslo = wshi + 262144;
    unsigned short* wohi = wslo + 262144;
    unsigned short* wolo = wohi + 262144;

    hipLaunchKernelGGL(prep, dim3(6272), dim3(256), 0, stream,
                       adj, Ws, Wo, x, nbrs, deg, wshi, wslo, wohi, wolo, xhi, xlo, N);
    hipLaunchKernelGGL((gemm_3t<false>), dim3(8, 64), dim3(256), 0, stream,
                       xhi, xlo, wshi, wslo, a1, a2, Wh, sbuf, dbuf, 4096, 512, 512);
    hipLaunchKernelGGL((attn_kernel<8, true, false>), dim3(4096), dim3(256), 0, stream,
                       Wh, sbuf, dbuf, nbrs, deg, (float*)nullptr, hch, hcl, N);
    hipLaunchKernelGGL((gemm_3t<true>), dim3(8, 64), dim3(256), 0, stream,
                       hch, hcl, wohi, wolo, ao1, ao2, Who, spart, dpart, 4096, 512, 512);
    hipLaunchKernelGGL((attn_kernel<1, false, true>), dim3(4096), dim3(256), 0, stream,
                       Who, spart, dpart, nbrs, deg, out, (unsigned short*)nullptr,
                       (unsigned short*)nullptr, N);
}